// Round 2
// baseline (1750.128 us; speedup 1.0000x reference)
//
#include <hip/hip_runtime.h>
#include <math.h>

#define NB 2
#define NS 2048
#define ND 1024
#define NH 16
#define NDH 64
#define NM (NB * NS)  // 4096

// ---------------------------------------------------------------------------
// QKV projection: Q/K/V = x @ W + b, written as [B,H,S,DH]
// grid (16 n-tiles, 64 m-tiles, 3 {q,k,v}), block 256
// ---------------------------------------------------------------------------
__global__ __launch_bounds__(256) void qkv_gemm(
    const float* __restrict__ x,
    const float* __restrict__ Wq, const float* __restrict__ bq,
    const float* __restrict__ Wk, const float* __restrict__ bk,
    const float* __restrict__ Wv, const float* __restrict__ bv,
    float* __restrict__ Qo, float* __restrict__ Ko, float* __restrict__ Vo)
{
    const int which = blockIdx.z;
    const float* __restrict__ Wm   = (which == 0) ? Wq : (which == 1) ? Wk : Wv;
    const float* __restrict__ bias = (which == 0) ? bq : (which == 1) ? bk : bv;
    float* __restrict__ dst        = (which == 0) ? Qo : (which == 1) ? Ko : Vo;

    const int head = blockIdx.x;      // 64-col n-tile == one head
    const int n0 = head * 64;
    const int m0 = blockIdx.y * 64;
    const int tid = threadIdx.x;
    const int tx = tid & 15, ty = tid >> 4;

    __shared__ float As[16][68];  // [kk][row]
    __shared__ float Bs[16][68];  // [kk][col]

    const int arow = tid >> 2;          // 0..63
    const int acol = (tid & 3) << 2;    // 0,4,8,12
    const int brow = tid >> 4;          // 0..15
    const int bcol = (tid & 15) << 2;   // 0..60

    float acc[4][4] = {};

    for (int k0 = 0; k0 < ND; k0 += 16) {
        float4 a = *(const float4*)&x[(m0 + arow) * ND + k0 + acol];
        float4 b = *(const float4*)&Wm[(k0 + brow) * ND + n0 + bcol];
        __syncthreads();
        As[acol + 0][arow] = a.x;
        As[acol + 1][arow] = a.y;
        As[acol + 2][arow] = a.z;
        As[acol + 3][arow] = a.w;
        *(float4*)&Bs[brow][bcol] = b;
        __syncthreads();
#pragma unroll
        for (int kk = 0; kk < 16; ++kk) {
            float4 av  = *(const float4*)&As[kk][ty << 2];
            float4 bv4 = *(const float4*)&Bs[kk][tx << 2];
            const float aa[4] = {av.x, av.y, av.z, av.w};
            const float bb[4] = {bv4.x, bv4.y, bv4.z, bv4.w};
#pragma unroll
            for (int i = 0; i < 4; ++i)
#pragma unroll
                for (int j = 0; j < 4; ++j)
                    acc[i][j] += aa[i] * bb[j];
        }
    }

    float4 b4 = *(const float4*)&bias[n0 + (tx << 2)];
    const float bb4[4] = {b4.x, b4.y, b4.z, b4.w};
#pragma unroll
    for (int i = 0; i < 4; ++i) {
        int m = m0 + (ty << 2) + i;
        int b = m >> 11;             // m / NS
        int s = m & (NS - 1);
        float4 o;
        o.x = acc[i][0] + bb4[0];
        o.y = acc[i][1] + bb4[1];
        o.z = acc[i][2] + bb4[2];
        o.w = acc[i][3] + bb4[3];
        *(float4*)&dst[((size_t)(b * NH + head) * NS + s) * NDH + (tx << 2)] = o;
    }
}

// ---------------------------------------------------------------------------
// Flash attention fp32: per block one (b,h) and a 64-row Q tile.
// K tile buffer is reused for P after QK^T; V stored transposed in LDS.
// grid (S/64, B*H), block 256
// ---------------------------------------------------------------------------
__global__ __launch_bounds__(256) void attn_fwd(
    const float* __restrict__ Q, const float* __restrict__ K,
    const float* __restrict__ V, float* __restrict__ O)
{
    const int bh = blockIdx.y;
    const int q0 = blockIdx.x * 64;
    const int tid = threadIdx.x;
    const int tx = tid & 15, ty = tid >> 4;

    __shared__ float Qs[64][68];
    __shared__ float KPs[64][68];  // K tile, then reused as P tile
    __shared__ float Vt[64][68];   // transposed: [dh][kv]

    const float* __restrict__ Qb = Q + (size_t)bh * NS * NDH;
    const float* __restrict__ Kb = K + (size_t)bh * NS * NDH;
    const float* __restrict__ Vb = V + (size_t)bh * NS * NDH;

#pragma unroll
    for (int t = 0; t < 4; ++t) {
        int idx = tid + t * 256;
        int r = idx >> 4, c = (idx & 15) << 2;
        *(float4*)&Qs[r][c] = *(const float4*)&Qb[(q0 + r) * NDH + c];
    }

    float m_run[4], l_run[4], oacc[4][4] = {};
#pragma unroll
    for (int i = 0; i < 4; ++i) { m_run[i] = -INFINITY; l_run[i] = 0.f; }

    const float scale = 0.125f;  // 1/sqrt(64)

    for (int kv0 = 0; kv0 < NS; kv0 += 64) {
        __syncthreads();  // prev PV done before K/V overwrite
#pragma unroll
        for (int t = 0; t < 4; ++t) {
            int idx = tid + t * 256;
            int r = idx >> 4, c = (idx & 15) << 2;
            *(float4*)&KPs[r][c] = *(const float4*)&Kb[(kv0 + r) * NDH + c];
            float4 v4 = *(const float4*)&Vb[(kv0 + r) * NDH + c];
            Vt[c + 0][r] = v4.x;
            Vt[c + 1][r] = v4.y;
            Vt[c + 2][r] = v4.z;
            Vt[c + 3][r] = v4.w;
        }
        __syncthreads();

        // S = (Q @ K^T) * scale
        float sacc[4][4] = {};
#pragma unroll
        for (int k4 = 0; k4 < 16; ++k4) {
            float4 qa[4], kb4[4];
#pragma unroll
            for (int i = 0; i < 4; ++i) qa[i] = *(const float4*)&Qs[ty + 16 * i][k4 << 2];
#pragma unroll
            for (int j = 0; j < 4; ++j) kb4[j] = *(const float4*)&KPs[tx + 16 * j][k4 << 2];
#pragma unroll
            for (int i = 0; i < 4; ++i)
#pragma unroll
                for (int j = 0; j < 4; ++j)
                    sacc[i][j] += qa[i].x * kb4[j].x + qa[i].y * kb4[j].y +
                                  qa[i].z * kb4[j].z + qa[i].w * kb4[j].w;
        }

        // online softmax (rows = ty + 16*i, replicated across the 16 tx lanes)
        float pr[4][4];
#pragma unroll
        for (int i = 0; i < 4; ++i) {
            float tm = -INFINITY;
#pragma unroll
            for (int j = 0; j < 4; ++j) {
                sacc[i][j] *= scale;
                tm = fmaxf(tm, sacc[i][j]);
            }
#pragma unroll
            for (int off = 1; off < 16; off <<= 1)
                tm = fmaxf(tm, __shfl_xor(tm, off));
            float mn = fmaxf(m_run[i], tm);
            float alpha = __expf(m_run[i] - mn);
            float rs = 0.f;
#pragma unroll
            for (int j = 0; j < 4; ++j) {
                pr[i][j] = __expf(sacc[i][j] - mn);
                rs += pr[i][j];
            }
#pragma unroll
            for (int off = 1; off < 16; off <<= 1)
                rs += __shfl_xor(rs, off);
            l_run[i] = l_run[i] * alpha + rs;
            m_run[i] = mn;
#pragma unroll
            for (int j = 0; j < 4; ++j) oacc[i][j] *= alpha;
        }

        __syncthreads();  // all S-gemm reads of K done before P overwrite
#pragma unroll
        for (int i = 0; i < 4; ++i)
#pragma unroll
            for (int j = 0; j < 4; ++j)
                KPs[ty + 16 * i][tx + 16 * j] = pr[i][j];
        __syncthreads();

        // O += P @ V   (Vt is [dh][kv], so both operands read float4 over kv)
#pragma unroll
        for (int k4 = 0; k4 < 16; ++k4) {
            float4 pa[4], vb4[4];
#pragma unroll
            for (int i = 0; i < 4; ++i) pa[i] = *(const float4*)&KPs[ty + 16 * i][k4 << 2];
#pragma unroll
            for (int j = 0; j < 4; ++j) vb4[j] = *(const float4*)&Vt[tx + 16 * j][k4 << 2];
#pragma unroll
            for (int i = 0; i < 4; ++i)
#pragma unroll
                for (int j = 0; j < 4; ++j)
                    oacc[i][j] += pa[i].x * vb4[j].x + pa[i].y * vb4[j].y +
                                  pa[i].z * vb4[j].z + pa[i].w * vb4[j].w;
        }
    }

    float* __restrict__ Ob = O + (size_t)bh * NS * NDH;
#pragma unroll
    for (int i = 0; i < 4; ++i) {
        float inv = 1.0f / l_run[i];
#pragma unroll
        for (int j = 0; j < 4; ++j)
            Ob[(q0 + ty + 16 * i) * NDH + tx + 16 * j] = oacc[i][j] * inv;
    }
}

// ---------------------------------------------------------------------------
// Output projection: out = attn([B,H,S,DH] gathered to [B,S,D]) @ Wo + bo
// grid (16, 64), block 256
// ---------------------------------------------------------------------------
__global__ __launch_bounds__(256) void out_gemm(
    const float* __restrict__ Aattn, const float* __restrict__ Wo,
    const float* __restrict__ bo, float* __restrict__ out)
{
    const int n0 = blockIdx.x * 64;
    const int m0 = blockIdx.y * 64;
    const int tid = threadIdx.x;
    const int tx = tid & 15, ty = tid >> 4;

    __shared__ float As[16][68];
    __shared__ float Bs[16][68];

    const int arow = tid >> 2;
    const int acol = (tid & 3) << 2;
    const int brow = tid >> 4;
    const int bcol = (tid & 15) << 2;

    const int m = m0 + arow;
    const int b = m >> 11;
    const int s = m & (NS - 1);

    float acc[4][4] = {};

    for (int k0 = 0; k0 < ND; k0 += 16) {
        int h = k0 >> 6;
        int dh = (k0 & 63) + acol;
        float4 a = *(const float4*)&Aattn[((size_t)(b * NH + h) * NS + s) * NDH + dh];
        float4 w4 = *(const float4*)&Wo[(k0 + brow) * ND + n0 + bcol];
        __syncthreads();
        As[acol + 0][arow] = a.x;
        As[acol + 1][arow] = a.y;
        As[acol + 2][arow] = a.z;
        As[acol + 3][arow] = a.w;
        *(float4*)&Bs[brow][bcol] = w4;
        __syncthreads();
#pragma unroll
        for (int kk = 0; kk < 16; ++kk) {
            float4 av  = *(const float4*)&As[kk][ty << 2];
            float4 bv4 = *(const float4*)&Bs[kk][tx << 2];
            const float aa[4] = {av.x, av.y, av.z, av.w};
            const float bb[4] = {bv4.x, bv4.y, bv4.z, bv4.w};
#pragma unroll
            for (int i = 0; i < 4; ++i)
#pragma unroll
                for (int j = 0; j < 4; ++j)
                    acc[i][j] += aa[i] * bb[j];
        }
    }

    float4 b4 = *(const float4*)&bo[n0 + (tx << 2)];
    const float bb4[4] = {b4.x, b4.y, b4.z, b4.w};
#pragma unroll
    for (int i = 0; i < 4; ++i) {
        int mm = m0 + (ty << 2) + i;
        float4 o;
        o.x = acc[i][0] + bb4[0];
        o.y = acc[i][1] + bb4[1];
        o.z = acc[i][2] + bb4[2];
        o.w = acc[i][3] + bb4[3];
        *(float4*)&out[(size_t)mm * ND + n0 + (tx << 2)] = o;
    }
}

// ---------------------------------------------------------------------------
extern "C" void kernel_launch(void* const* d_in, const int* in_sizes, int n_in,
                              void* d_out, int out_size, void* d_ws, size_t ws_size,
                              hipStream_t stream)
{
    const float* x  = (const float*)d_in[0];
    const float* Wq = (const float*)d_in[1];
    const float* bq = (const float*)d_in[2];
    const float* Wk = (const float*)d_in[3];
    const float* bk = (const float*)d_in[4];
    const float* Wv = (const float*)d_in[5];
    const float* bv = (const float*)d_in[6];
    const float* Wo = (const float*)d_in[7];
    const float* bo = (const float*)d_in[8];
    float* out = (float*)d_out;

    float* Qw = (float*)d_ws;                      // [B*H, S, DH] = 16 MB
    float* Kw = Qw + (size_t)NM * ND;              // 16 MB
    float* Vw = Kw + (size_t)NM * ND;              // 16 MB
    float* Aw = Vw + (size_t)NM * ND;              // attn out, 16 MB

    qkv_gemm<<<dim3(16, 64, 3), 256, 0, stream>>>(x, Wq, bq, Wk, bk, Wv, bv, Qw, Kw, Vw);
    attn_fwd<<<dim3(NS / 64, NB * NH), 256, 0, stream>>>(Qw, Kw, Vw, Aw);
    out_gemm<<<dim3(16, 64), 256, 0, stream>>>(Aw, Wo, bo, out);
}

// Round 3
// 696.459 us; speedup vs baseline: 2.5129x; 2.5129x over previous
//
#include <hip/hip_runtime.h>
#include <math.h>

#define NB 2
#define NS 2048
#define ND 1024
#define NH 16
#define NDH 64
#define NM (NB * NS)  // 4096

typedef unsigned short ushortT;
typedef __attribute__((ext_vector_type(8))) short bf16x8;   // 8 bf16 in 4 VGPRs
typedef __attribute__((ext_vector_type(4))) float f32x4;    // MFMA accumulator

__device__ inline unsigned short f2bf(float f) {
    union { float f; unsigned u; } v; v.f = f;
    unsigned r = v.u + 0x7FFFu + ((v.u >> 16) & 1u);  // RNE
    return (unsigned short)(r >> 16);
}

// ---------------------------------------------------------------------------
// QKV projection (fp32 core): Q/K/V = x @ W + b, written as [B,H,S,DH] in BF16
// grid (16 n-tiles==head, 64 m-tiles, 3 {q,k,v}), block 256
// ---------------------------------------------------------------------------
__global__ __launch_bounds__(256) void qkv_gemm(
    const float* __restrict__ x,
    const float* __restrict__ Wq, const float* __restrict__ bq,
    const float* __restrict__ Wk, const float* __restrict__ bk,
    const float* __restrict__ Wv, const float* __restrict__ bv,
    ushortT* __restrict__ Qo, ushortT* __restrict__ Ko, ushortT* __restrict__ Vo)
{
    const int which = blockIdx.z;
    const float* __restrict__ Wm   = (which == 0) ? Wq : (which == 1) ? Wk : Wv;
    const float* __restrict__ bias = (which == 0) ? bq : (which == 1) ? bk : bv;
    ushortT* __restrict__ dst      = (which == 0) ? Qo : (which == 1) ? Ko : Vo;

    const int head = blockIdx.x;
    const int n0 = head * 64;
    const int m0 = blockIdx.y * 64;
    const int tid = threadIdx.x;
    const int tx = tid & 15, ty = tid >> 4;

    __shared__ float As[16][68];
    __shared__ float Bs[16][68];

    const int arow = tid >> 2;
    const int acol = (tid & 3) << 2;
    const int brow = tid >> 4;
    const int bcol = (tid & 15) << 2;

    float acc[4][4] = {};

    for (int k0 = 0; k0 < ND; k0 += 16) {
        float4 a = *(const float4*)&x[(m0 + arow) * ND + k0 + acol];
        float4 b = *(const float4*)&Wm[(k0 + brow) * ND + n0 + bcol];
        __syncthreads();
        As[acol + 0][arow] = a.x;
        As[acol + 1][arow] = a.y;
        As[acol + 2][arow] = a.z;
        As[acol + 3][arow] = a.w;
        *(float4*)&Bs[brow][bcol] = b;
        __syncthreads();
#pragma unroll
        for (int kk = 0; kk < 16; ++kk) {
            float4 av  = *(const float4*)&As[kk][ty << 2];
            float4 bv4 = *(const float4*)&Bs[kk][tx << 2];
            const float aa[4] = {av.x, av.y, av.z, av.w};
            const float bb[4] = {bv4.x, bv4.y, bv4.z, bv4.w};
#pragma unroll
            for (int i = 0; i < 4; ++i)
#pragma unroll
                for (int j = 0; j < 4; ++j)
                    acc[i][j] += aa[i] * bb[j];
        }
    }

    float4 b4 = *(const float4*)&bias[n0 + (tx << 2)];
    const float bb4[4] = {b4.x, b4.y, b4.z, b4.w};
#pragma unroll
    for (int i = 0; i < 4; ++i) {
        int m = m0 + (ty << 2) + i;
        int b = m >> 11;
        int s = m & (NS - 1);
        uint2 pk;
        pk.x = (unsigned)f2bf(acc[i][0] + bb4[0]) | ((unsigned)f2bf(acc[i][1] + bb4[1]) << 16);
        pk.y = (unsigned)f2bf(acc[i][2] + bb4[2]) | ((unsigned)f2bf(acc[i][3] + bb4[3]) << 16);
        *(uint2*)&dst[((size_t)(b * NH + head) * NS + s) * NDH + (tx << 2)] = pk;
    }
}

// ---------------------------------------------------------------------------
// MFMA flash attention, bf16 inputs, fp32 softmax/accum.
// Block: 256 thr = 4 waves; wave w owns q-rows [q0+16w, q0+16w+16).
// KV tile = 64. K LDS chunk-swizzled; V transposed+kv-swizzled; P via LDS.
// grid (S/64, B*H)
// ---------------------------------------------------------------------------
__global__ __launch_bounds__(256) void attn_fwd_mfma(
    const ushortT* __restrict__ Q, const ushortT* __restrict__ K,
    const ushortT* __restrict__ V, float* __restrict__ O)
{
    const int bh = blockIdx.y;
    const int q0 = blockIdx.x * 64;
    const int tid  = threadIdx.x;
    const int lane = tid & 63;
    const int w    = tid >> 6;
    const int a = lane & 15;   // A-frag row / C-D col
    const int g = lane >> 4;   // k-group

    __shared__ __align__(16) ushortT Ks[64 * 64];      // [row][chunk^(row&7)]
    __shared__ __align__(16) ushortT Vt[64 * 72];      // [d][kv ^ ((d>>3)<<3)]
    __shared__ __align__(16) ushortT Ps[4][16 * 72];   // per-wave P

    const size_t base = (size_t)bh * NS * NDH;

    // Q fragments (A-operand): row a of wave's 16, k = g*8+j (+32)
    bf16x8 qf[2];
    {
        const ushortT* qrow = Q + base + (size_t)(q0 + w * 16 + a) * NDH + (g << 3);
        qf[0] = *(const bf16x8*)(qrow);
        qf[1] = *(const bf16x8*)(qrow + 32);
    }

    float m_run[4], l_run[4];
    f32x4 oacc[4] = {};
#pragma unroll
    for (int r = 0; r < 4; ++r) { m_run[r] = -INFINITY; l_run[r] = 0.f; }

    const float scale = 0.125f;  // 1/sqrt(64)

    for (int kv0 = 0; kv0 < NS; kv0 += 64) {
        __syncthreads();
        // ---- stage K tile (reg-staged, swizzled LDS placement) ----
#pragma unroll
        for (int i = 0; i < 2; ++i) {
            int idx = i * 256 + tid;           // 512 16B-chunks
            int r = idx >> 3, sc = idx & 7;
            bf16x8 k8 = *(const bf16x8*)&K[base + (size_t)(kv0 + r) * NDH + (sc << 3)];
            *(bf16x8*)&Ks[(r << 6) + ((sc ^ (r & 7)) << 3)] = k8;
        }
        // ---- stage V transposed, kv-index swizzled by d-chunk ----
#pragma unroll
        for (int i = 0; i < 2; ++i) {
            int idx = i * 256 + tid;
            int kvr = idx >> 3, c = idx & 7;
            bf16x8 v8 = *(const bf16x8*)&V[base + (size_t)(kv0 + kvr) * NDH + (c << 3)];
            int kvs = kvr ^ (c << 3);
#pragma unroll
            for (int j = 0; j < 8; ++j)
                Vt[(c * 8 + j) * 72 + kvs] = (ushortT)v8[j];
        }
        __syncthreads();

        // ---- S = Q K^T : 4 kv-subtiles x 2 k-chunks ----
        f32x4 sacc[4] = {};
#pragma unroll
        for (int s = 0; s < 4; ++s) {
#pragma unroll
            for (int kc = 0; kc < 2; ++kc) {
                bf16x8 kf = *(const bf16x8*)&Ks[((s * 16 + a) << 6) + (((g + 4 * kc) ^ (a & 7)) << 3)];
                sacc[s] = __builtin_amdgcn_mfma_f32_16x16x32_bf16(qf[kc], kf, sacc[s], 0, 0, 0);
            }
        }

        // ---- online softmax: lane holds rows g*4+r, cols s*16+a ----
        float alpha[4];
#pragma unroll
        for (int r = 0; r < 4; ++r) {
            float tm = fmaxf(fmaxf(sacc[0][r], sacc[1][r]), fmaxf(sacc[2][r], sacc[3][r])) * scale;
#pragma unroll
            for (int off = 1; off < 16; off <<= 1)
                tm = fmaxf(tm, __shfl_xor(tm, off));
            float mn = fmaxf(m_run[r], tm);
            alpha[r] = __expf(m_run[r] - mn);
            m_run[r] = mn;
            float rs = 0.f;
#pragma unroll
            for (int s = 0; s < 4; ++s) {
                float p = __expf(sacc[s][r] * scale - mn);
                sacc[s][r] = p;   // reuse as P
                rs += p;
            }
#pragma unroll
            for (int off = 1; off < 16; off <<= 1)
                rs += __shfl_xor(rs, off);
            l_run[r] = l_run[r] * alpha[r] + rs;
        }

        // ---- P -> per-wave LDS (D-layout -> A-layout reshape) ----
#pragma unroll
        for (int r = 0; r < 4; ++r)
#pragma unroll
            for (int s = 0; s < 4; ++s)
                Ps[w][(g * 4 + r) * 72 + (s * 16 + a)] = f2bf(sacc[s][r]);

        // ---- rescale O ----
#pragma unroll
        for (int d = 0; d < 4; ++d)
#pragma unroll
            for (int r = 0; r < 4; ++r)
                oacc[d][r] *= alpha[r];

        // ---- O += P V ----
        bf16x8 pf0 = *(const bf16x8*)&Ps[w][a * 72 + (g << 3)];
        bf16x8 pf1 = *(const bf16x8*)&Ps[w][a * 72 + (g << 3) + 32];
#pragma unroll
        for (int d = 0; d < 4; ++d) {
            int dsw = (((a >> 3) + 2 * d) & 7) << 3;
            bf16x8 vf0 = *(const bf16x8*)&Vt[(a + 16 * d) * 72 + (((g << 3) + 0)  ^ dsw)];
            bf16x8 vf1 = *(const bf16x8*)&Vt[(a + 16 * d) * 72 + (((g << 3) + 32) ^ dsw)];
            oacc[d] = __builtin_amdgcn_mfma_f32_16x16x32_bf16(pf0, vf0, oacc[d], 0, 0, 0);
            oacc[d] = __builtin_amdgcn_mfma_f32_16x16x32_bf16(pf1, vf1, oacc[d], 0, 0, 0);
        }
    }

    float* __restrict__ Ob = O + base;
#pragma unroll
    for (int r = 0; r < 4; ++r) {
        float inv = 1.0f / l_run[r];
        size_t row = (size_t)(q0 + w * 16 + g * 4 + r) * NDH;
#pragma unroll
        for (int d = 0; d < 4; ++d)
            Ob[row + d * 16 + a] = oacc[d][r] * inv;
    }
}

// ---------------------------------------------------------------------------
// Output projection (fp32): out = attn([B,H,S,DH] gathered) @ Wo + bo
// grid (16, 64), block 256
// ---------------------------------------------------------------------------
__global__ __launch_bounds__(256) void out_gemm(
    const float* __restrict__ Aattn, const float* __restrict__ Wo,
    const float* __restrict__ bo, float* __restrict__ out)
{
    const int n0 = blockIdx.x * 64;
    const int m0 = blockIdx.y * 64;
    const int tid = threadIdx.x;
    const int tx = tid & 15, ty = tid >> 4;

    __shared__ float As[16][68];
    __shared__ float Bs[16][68];

    const int arow = tid >> 2;
    const int acol = (tid & 3) << 2;
    const int brow = tid >> 4;
    const int bcol = (tid & 15) << 2;

    const int m = m0 + arow;
    const int b = m >> 11;
    const int s = m & (NS - 1);

    float acc[4][4] = {};

    for (int k0 = 0; k0 < ND; k0 += 16) {
        int h = k0 >> 6;
        int dh = (k0 & 63) + acol;
        float4 a = *(const float4*)&Aattn[((size_t)(b * NH + h) * NS + s) * NDH + dh];
        float4 w4 = *(const float4*)&Wo[(k0 + brow) * ND + n0 + bcol];
        __syncthreads();
        As[acol + 0][arow] = a.x;
        As[acol + 1][arow] = a.y;
        As[acol + 2][arow] = a.z;
        As[acol + 3][arow] = a.w;
        *(float4*)&Bs[brow][bcol] = w4;
        __syncthreads();
#pragma unroll
        for (int kk = 0; kk < 16; ++kk) {
            float4 av  = *(const float4*)&As[kk][ty << 2];
            float4 bv4 = *(const float4*)&Bs[kk][tx << 2];
            const float aa[4] = {av.x, av.y, av.z, av.w};
            const float bb[4] = {bv4.x, bv4.y, bv4.z, bv4.w};
#pragma unroll
            for (int i = 0; i < 4; ++i)
#pragma unroll
                for (int j = 0; j < 4; ++j)
                    acc[i][j] += aa[i] * bb[j];
        }
    }

    float4 b4 = *(const float4*)&bo[n0 + (tx << 2)];
    const float bb4[4] = {b4.x, b4.y, b4.z, b4.w};
#pragma unroll
    for (int i = 0; i < 4; ++i) {
        int mm = m0 + (ty << 2) + i;
        float4 o;
        o.x = acc[i][0] + bb4[0];
        o.y = acc[i][1] + bb4[1];
        o.z = acc[i][2] + bb4[2];
        o.w = acc[i][3] + bb4[3];
        *(float4*)&out[(size_t)mm * ND + n0 + (tx << 2)] = o;
    }
}

// ---------------------------------------------------------------------------
extern "C" void kernel_launch(void* const* d_in, const int* in_sizes, int n_in,
                              void* d_out, int out_size, void* d_ws, size_t ws_size,
                              hipStream_t stream)
{
    const float* x  = (const float*)d_in[0];
    const float* Wq = (const float*)d_in[1];
    const float* bq = (const float*)d_in[2];
    const float* Wk = (const float*)d_in[3];
    const float* bk = (const float*)d_in[4];
    const float* Wv = (const float*)d_in[5];
    const float* bv = (const float*)d_in[6];
    const float* Wo = (const float*)d_in[7];
    const float* bo = (const float*)d_in[8];
    float* out = (float*)d_out;

    ushortT* Qb = (ushortT*)d_ws;                  // [B*H,S,DH] bf16, 8 MB
    ushortT* Kb = Qb + (size_t)NM * ND;            // 8 MB
    ushortT* Vb = Kb + (size_t)NM * ND;            // 8 MB
    float*   Aw = (float*)(Vb + (size_t)NM * ND);  // attn out fp32, 16 MB

    qkv_gemm<<<dim3(16, 64, 3), 256, 0, stream>>>(x, Wq, bq, Wk, bk, Wv, bv, Qb, Kb, Vb);
    attn_fwd_mfma<<<dim3(NS / 64, NB * NH), 256, 0, stream>>>(Qb, Kb, Vb, Aw);
    out_gemm<<<dim3(16, 64), 256, 0, stream>>>(Aw, Wo, bo, out);
}

// Round 4
// 353.662 us; speedup vs baseline: 4.9486x; 1.9693x over previous
//
#include <hip/hip_runtime.h>
#include <math.h>

#define NB 2
#define NS 2048
#define ND 1024
#define NH 16
#define NDH 64
#define NM (NB * NS)   // 4096 rows total
#define K2 (2 * ND)    // 2048: stored split width [hi | lo]
#define K3 (3 * ND)    // 3072: virtual K for hh+hl+lh

typedef unsigned short ushortT;
typedef __attribute__((ext_vector_type(8))) short bf16x8;   // 8 bf16 = 4 VGPRs
typedef __attribute__((ext_vector_type(4))) float f32x4;    // MFMA accumulator

__device__ inline unsigned short f2bf(float f) {
    union { float f; unsigned u; } v; v.f = f;
    unsigned r = v.u + 0x7FFFu + ((v.u >> 16) & 1u);  // RNE
    return (unsigned short)(r >> 16);
}
__device__ inline float bf2f(unsigned short h) {
    union { unsigned u; float f; } v; v.u = ((unsigned)h) << 16; return v.f;
}
// async global->LDS, 16 bytes per lane; lds base must be wave-uniform
__device__ inline void gl_lds16(const ushortT* g, ushortT* l) {
    __builtin_amdgcn_global_load_lds(
        (const __attribute__((address_space(1))) unsigned*)g,
        (__attribute__((address_space(3))) unsigned*)l, 16, 0, 0);
}

// ---------------------------------------------------------------------------
// split_x: x fp32 [NM x ND] -> x2 bf16 [NM x K2] = [hi | lo]
// ---------------------------------------------------------------------------
__global__ __launch_bounds__(256) void split_x(
    const float* __restrict__ x, ushortT* __restrict__ x2)
{
    int idx = (blockIdx.x * 256 + threadIdx.x) * 4;
    int row = idx >> 10, col = idx & 1023;
    float4 v = *(const float4*)&x[idx];
    float fv[4] = {v.x, v.y, v.z, v.w};
    unsigned short h[4], l[4];
#pragma unroll
    for (int j = 0; j < 4; ++j) {
        h[j] = f2bf(fv[j]);
        l[j] = f2bf(fv[j] - bf2f(h[j]));
    }
    uint2 hp, lp;
    hp.x = (unsigned)h[0] | ((unsigned)h[1] << 16);
    hp.y = (unsigned)h[2] | ((unsigned)h[3] << 16);
    lp.x = (unsigned)l[0] | ((unsigned)l[1] << 16);
    lp.y = (unsigned)l[2] | ((unsigned)l[3] << 16);
    *(uint2*)&x2[(size_t)row * K2 + col]      = hp;
    *(uint2*)&x2[(size_t)row * K2 + ND + col] = lp;
}

// ---------------------------------------------------------------------------
// split_w_t: W fp32 [ND x ND] -> Wt bf16 [ND x K2] = [hi(W^T) | lo(W^T)]
// grid (16,16,4): z picks Wq/Wk/Wv/Wo
// ---------------------------------------------------------------------------
__global__ __launch_bounds__(256) void split_w_t(
    const float* __restrict__ Wq, const float* __restrict__ Wk,
    const float* __restrict__ Wv, const float* __restrict__ Wo,
    ushortT* __restrict__ Wt)
{
    const int z = blockIdx.z;
    const float* __restrict__ W = (z == 0) ? Wq : (z == 1) ? Wk : (z == 2) ? Wv : Wo;
    ushortT* __restrict__ dst = Wt + (size_t)z * ND * K2;

    const int k0 = blockIdx.y * 64, n0 = blockIdx.x * 64;
    const int t = threadIdx.x;
    __shared__ float Ls[64][65];

#pragma unroll
    for (int i = 0; i < 4; ++i) {
        int kl = i * 16 + (t >> 4);
        int nl = (t & 15) << 2;
        float4 w4 = *(const float4*)&W[(size_t)(k0 + kl) * ND + n0 + nl];
        Ls[nl + 0][kl] = w4.x;
        Ls[nl + 1][kl] = w4.y;
        Ls[nl + 2][kl] = w4.z;
        Ls[nl + 3][kl] = w4.w;
    }
    __syncthreads();
#pragma unroll
    for (int i = 0; i < 16; ++i) {
        int flat = i * 256 + t;
        int n = flat >> 6, kk = flat & 63;
        float val = Ls[n][kk];
        unsigned short hi = f2bf(val);
        dst[(size_t)(n0 + n) * K2 + (k0 + kk)]      = hi;
        dst[(size_t)(n0 + n) * K2 + ND + (k0 + kk)] = f2bf(val - bf2f(hi));
    }
}

// ---------------------------------------------------------------------------
// Split-bf16 GEMM, m97 structure: 128x128 tile, BK=32, 4 waves, gl_lds16.
// Virtual K=3072: A thirds [hi,hi,lo] (stored [hi|lo]), B thirds [hi,lo,hi].
// OUTMODE 0: qkv (z=0..2 -> Q/K/V bf16 [B,H,S,DH]); OUTMODE 1: fp32 [NM x ND].
// ---------------------------------------------------------------------------
template <int OUTMODE>
__global__ __launch_bounds__(256) void gemm_split(
    const ushortT* __restrict__ A2,   // [NM x K2]
    const ushortT* __restrict__ Wt,   // base of weight split-transpose mats
    const float* __restrict__ b0, const float* __restrict__ b1, const float* __restrict__ b2,
    ushortT* __restrict__ Qo, ushortT* __restrict__ Ko, ushortT* __restrict__ Vo,
    float* __restrict__ Ofp)
{
    const int z = blockIdx.z;
    const ushortT* __restrict__ Bt = Wt + (size_t)z * ND * K2;
    const float* __restrict__ bias = (z == 0) ? b0 : (z == 1) ? b1 : b2;
    ushortT* __restrict__ obf = (z == 0) ? Qo : (z == 1) ? Ko : Vo;

    const int m0 = blockIdx.y * 128;
    const int n0 = blockIdx.x * 128;
    const int tid = threadIdx.x;
    const int lane = tid & 63, w = tid >> 6;
    const int wrow = w >> 1, wcol = w & 1;
    const int a = lane & 15, g = lane >> 4;

    __shared__ __align__(16) ushortT Abuf[128 * 32];
    __shared__ __align__(16) ushortT Bbuf[128 * 32];

    f32x4 acc[4][4] = {};

    const int srow_l = tid >> 2;        // row within 64-row stage group
    const int scc0 = tid & 3;
    const int swz = (a >> 1) & 3;

    for (int ks = 0; ks < K3 / 32; ++ks) {
        const int kp = ks * 32;
        const int ac = (kp < ND) ? kp : kp - ND;        // A: [hi,hi,lo]
        const int bc = (kp < 2 * ND) ? kp : kp - 2 * ND; // B: [hi,lo,hi]
        __syncthreads();
#pragma unroll
        for (int t = 0; t < 2; ++t) {
            int r = t * 64 + srow_l;
            int sc = scc0 ^ ((r >> 1) & 3);
            gl_lds16(&A2[(size_t)(m0 + r) * K2 + ac + (sc << 3)],
                     &Abuf[(t * 256 + w * 64) * 8]);
            gl_lds16(&Bt[(size_t)(n0 + r) * K2 + bc + (sc << 3)],
                     &Bbuf[(t * 256 + w * 64) * 8]);
        }
        __syncthreads();

        bf16x8 af[4], bfr[4];
#pragma unroll
        for (int i = 0; i < 4; ++i)
            af[i] = *(const bf16x8*)&Abuf[(wrow * 64 + i * 16 + a) * 32 + ((g ^ swz) << 3)];
#pragma unroll
        for (int j = 0; j < 4; ++j)
            bfr[j] = *(const bf16x8*)&Bbuf[(wcol * 64 + j * 16 + a) * 32 + ((g ^ swz) << 3)];
#pragma unroll
        for (int i = 0; i < 4; ++i)
#pragma unroll
            for (int j = 0; j < 4; ++j)
                acc[i][j] = __builtin_amdgcn_mfma_f32_16x16x32_bf16(af[i], bfr[j], acc[i][j], 0, 0, 0);
    }

    float bj[4];
#pragma unroll
    for (int j = 0; j < 4; ++j) bj[j] = bias[n0 + wcol * 64 + j * 16 + a];

#pragma unroll
    for (int i = 0; i < 4; ++i) {
#pragma unroll
        for (int r = 0; r < 4; ++r) {
            int grow = m0 + wrow * 64 + i * 16 + g * 4 + r;
#pragma unroll
            for (int j = 0; j < 4; ++j) {
                int gcol = n0 + wcol * 64 + j * 16 + a;
                float v = acc[i][j][r] + bj[j];
                if (OUTMODE == 0) {
                    int b = grow >> 11, s = grow & (NS - 1);
                    obf[((size_t)(b * NH + (gcol >> 6)) * NS + s) * NDH + (gcol & 63)] = f2bf(v);
                } else {
                    Ofp[(size_t)grow * ND + gcol] = v;
                }
            }
        }
    }
}

// ---------------------------------------------------------------------------
// MFMA flash attention (unchanged core); epilogue writes gathered split
// output A2 [NM x K2] = [hi | lo] at cols h*64+dh, for the out-projection.
// ---------------------------------------------------------------------------
__global__ __launch_bounds__(256) void attn_fwd_mfma(
    const ushortT* __restrict__ Q, const ushortT* __restrict__ K,
    const ushortT* __restrict__ V, ushortT* __restrict__ A2o)
{
    const int bh = blockIdx.y;
    const int q0 = blockIdx.x * 64;
    const int tid  = threadIdx.x;
    const int lane = tid & 63;
    const int w    = tid >> 6;
    const int a = lane & 15;
    const int g = lane >> 4;

    __shared__ __align__(16) ushortT Ks[64 * 64];
    __shared__ __align__(16) ushortT Vt[64 * 72];
    __shared__ __align__(16) ushortT Ps[4][16 * 72];

    const size_t base = (size_t)bh * NS * NDH;

    bf16x8 qf[2];
    {
        const ushortT* qrow = Q + base + (size_t)(q0 + w * 16 + a) * NDH + (g << 3);
        qf[0] = *(const bf16x8*)(qrow);
        qf[1] = *(const bf16x8*)(qrow + 32);
    }

    float m_run[4], l_run[4];
    f32x4 oacc[4] = {};
#pragma unroll
    for (int r = 0; r < 4; ++r) { m_run[r] = -INFINITY; l_run[r] = 0.f; }

    const float scale = 0.125f;

    for (int kv0 = 0; kv0 < NS; kv0 += 64) {
        __syncthreads();
#pragma unroll
        for (int i = 0; i < 2; ++i) {
            int idx = i * 256 + tid;
            int r = idx >> 3, sc = idx & 7;
            bf16x8 k8 = *(const bf16x8*)&K[base + (size_t)(kv0 + r) * NDH + (sc << 3)];
            *(bf16x8*)&Ks[(r << 6) + ((sc ^ (r & 7)) << 3)] = k8;
        }
#pragma unroll
        for (int i = 0; i < 2; ++i) {
            int idx = i * 256 + tid;
            int kvr = idx >> 3, c = idx & 7;
            bf16x8 v8 = *(const bf16x8*)&V[base + (size_t)(kv0 + kvr) * NDH + (c << 3)];
            int kvs = kvr ^ (c << 3);
#pragma unroll
            for (int j = 0; j < 8; ++j)
                Vt[(c * 8 + j) * 72 + kvs] = (ushortT)v8[j];
        }
        __syncthreads();

        f32x4 sacc[4] = {};
#pragma unroll
        for (int s = 0; s < 4; ++s) {
#pragma unroll
            for (int kc = 0; kc < 2; ++kc) {
                bf16x8 kf = *(const bf16x8*)&Ks[((s * 16 + a) << 6) + (((g + 4 * kc) ^ (a & 7)) << 3)];
                sacc[s] = __builtin_amdgcn_mfma_f32_16x16x32_bf16(qf[kc], kf, sacc[s], 0, 0, 0);
            }
        }

        float alpha[4];
#pragma unroll
        for (int r = 0; r < 4; ++r) {
            float tm = fmaxf(fmaxf(sacc[0][r], sacc[1][r]), fmaxf(sacc[2][r], sacc[3][r])) * scale;
#pragma unroll
            for (int off = 1; off < 16; off <<= 1)
                tm = fmaxf(tm, __shfl_xor(tm, off));
            float mn = fmaxf(m_run[r], tm);
            alpha[r] = __expf(m_run[r] - mn);
            m_run[r] = mn;
            float rs = 0.f;
#pragma unroll
            for (int s = 0; s < 4; ++s) {
                float p = __expf(sacc[s][r] * scale - mn);
                sacc[s][r] = p;
                rs += p;
            }
#pragma unroll
            for (int off = 1; off < 16; off <<= 1)
                rs += __shfl_xor(rs, off);
            l_run[r] = l_run[r] * alpha[r] + rs;
        }

#pragma unroll
        for (int r = 0; r < 4; ++r)
#pragma unroll
            for (int s = 0; s < 4; ++s)
                Ps[w][(g * 4 + r) * 72 + (s * 16 + a)] = f2bf(sacc[s][r]);

#pragma unroll
        for (int d = 0; d < 4; ++d)
#pragma unroll
            for (int r = 0; r < 4; ++r)
                oacc[d][r] *= alpha[r];

        bf16x8 pf0 = *(const bf16x8*)&Ps[w][a * 72 + (g << 3)];
        bf16x8 pf1 = *(const bf16x8*)&Ps[w][a * 72 + (g << 3) + 32];
#pragma unroll
        for (int d = 0; d < 4; ++d) {
            int dsw = (((a >> 3) + 2 * d) & 7) << 3;
            bf16x8 vf0 = *(const bf16x8*)&Vt[(a + 16 * d) * 72 + (((g << 3) + 0)  ^ dsw)];
            bf16x8 vf1 = *(const bf16x8*)&Vt[(a + 16 * d) * 72 + (((g << 3) + 32) ^ dsw)];
            oacc[d] = __builtin_amdgcn_mfma_f32_16x16x32_bf16(pf0, vf0, oacc[d], 0, 0, 0);
            oacc[d] = __builtin_amdgcn_mfma_f32_16x16x32_bf16(pf1, vf1, oacc[d], 0, 0, 0);
        }
    }

    const int b = bh >> 4, h = bh & 15;
#pragma unroll
    for (int r = 0; r < 4; ++r) {
        float inv = 1.0f / l_run[r];
        int s = q0 + w * 16 + g * 4 + r;
        size_t rowoff = (size_t)(b * NS + s) * K2;
#pragma unroll
        for (int d = 0; d < 4; ++d) {
            float o = oacc[d][r] * inv;
            unsigned short hi = f2bf(o);
            unsigned short lo = f2bf(o - bf2f(hi));
            int col = h * 64 + d * 16 + a;
            A2o[rowoff + col]      = hi;
            A2o[rowoff + ND + col] = lo;
        }
    }
}

// ---------------------------------------------------------------------------
extern "C" void kernel_launch(void* const* d_in, const int* in_sizes, int n_in,
                              void* d_out, int out_size, void* d_ws, size_t ws_size,
                              hipStream_t stream)
{
    const float* x  = (const float*)d_in[0];
    const float* Wq = (const float*)d_in[1];
    const float* bq = (const float*)d_in[2];
    const float* Wk = (const float*)d_in[3];
    const float* bk = (const float*)d_in[4];
    const float* Wv = (const float*)d_in[5];
    const float* bv = (const float*)d_in[6];
    const float* Wo = (const float*)d_in[7];
    const float* bo = (const float*)d_in[8];
    float* out = (float*)d_out;

    // workspace: x2/A2 (16.8MB) | Wt x4 (16.8MB) | Q,K,V bf16 (25.2MB) = 58.8MB
    ushortT* x2 = (ushortT*)d_ws;                      // [NM x K2]; later attn out
    ushortT* Wt = x2 + (size_t)NM * K2;                // 4 x [ND x K2]
    ushortT* Qb = Wt + (size_t)4 * ND * K2;
    ushortT* Kb = Qb + (size_t)NM * ND;
    ushortT* Vb = Kb + (size_t)NM * ND;

    split_x<<<dim3(NM * ND / 1024), 256, 0, stream>>>(x, x2);
    split_w_t<<<dim3(16, 16, 4), 256, 0, stream>>>(Wq, Wk, Wv, Wo, Wt);
    gemm_split<0><<<dim3(8, 32, 3), 256, 0, stream>>>(
        x2, Wt, bq, bk, bv, Qb, Kb, Vb, nullptr);
    attn_fwd_mfma<<<dim3(NS / 64, NB * NH), 256, 0, stream>>>(Qb, Kb, Vb, x2);
    gemm_split<1><<<dim3(8, 32, 1), 256, 0, stream>>>(
        x2, Wt + (size_t)3 * ND * K2, bo, bo, bo, nullptr, nullptr, nullptr, out);
}

// Round 5
// 255.711 us; speedup vs baseline: 6.8442x; 1.3831x over previous
//
#include <hip/hip_runtime.h>
#include <math.h>

#define NB 2
#define NS 2048
#define ND 1024
#define NH 16
#define NDH 64
#define NM (NB * NS)   // 4096 rows total
#define K2 (2 * ND)    // 2048: split width [hi | lo]

typedef unsigned short ushortT;
typedef __attribute__((ext_vector_type(8))) short bf16x8;   // 8 bf16 = 4 VGPRs
typedef __attribute__((ext_vector_type(4))) float f32x4;
typedef __attribute__((ext_vector_type(16))) float f32x16;  // 32x32 accumulator

__device__ inline unsigned short f2bf(float f) {
    union { float f; unsigned u; } v; v.f = f;
    unsigned r = v.u + 0x7FFFu + ((v.u >> 16) & 1u);  // RNE
    return (unsigned short)(r >> 16);
}
__device__ inline float bf2f(unsigned short h) {
    union { unsigned u; float f; } v; v.u = ((unsigned)h) << 16; return v.f;
}
__device__ inline void gl_lds16(const ushortT* g, ushortT* l) {
    __builtin_amdgcn_global_load_lds(
        (const __attribute__((address_space(1))) unsigned*)g,
        (__attribute__((address_space(3))) unsigned*)l, 16, 0, 0);
}

// ---------------------------------------------------------------------------
// split_x: x fp32 [NM x ND] -> x_hi bf16 [NM x ND]
// ---------------------------------------------------------------------------
__global__ __launch_bounds__(256) void split_x(
    const float* __restrict__ x, ushortT* __restrict__ xh)
{
    int idx = (blockIdx.x * 256 + threadIdx.x) * 4;
    float4 v = *(const float4*)&x[idx];
    float fv[4] = {v.x, v.y, v.z, v.w};
    union { ushortT s[4]; uint2 u; } o;
#pragma unroll
    for (int j = 0; j < 4; ++j) o.s[j] = f2bf(fv[j]);
    *(uint2*)&xh[idx] = o.u;
}

// ---------------------------------------------------------------------------
// split_w_t: W fp32 [K x N] -> transposed bf16.
// z<3: hi-only to WtH[z] ([ND x ND]); z==3: hi|lo to WtO ([ND x K2]).
// grid (16,16,4)
// ---------------------------------------------------------------------------
__global__ __launch_bounds__(256) void split_w_t(
    const float* __restrict__ Wq, const float* __restrict__ Wk,
    const float* __restrict__ Wv, const float* __restrict__ Wo,
    ushortT* __restrict__ WtH, ushortT* __restrict__ WtO)
{
    const int z = blockIdx.z;
    const float* __restrict__ W = (z == 0) ? Wq : (z == 1) ? Wk : (z == 2) ? Wv : Wo;

    const int k0 = blockIdx.y * 64, n0 = blockIdx.x * 64;
    const int t = threadIdx.x;
    __shared__ float Ls[64][65];

#pragma unroll
    for (int i = 0; i < 4; ++i) {
        int kl = i * 16 + (t >> 4);
        int nl = (t & 15) << 2;
        float4 w4 = *(const float4*)&W[(size_t)(k0 + kl) * ND + n0 + nl];
        Ls[nl + 0][kl] = w4.x;
        Ls[nl + 1][kl] = w4.y;
        Ls[nl + 2][kl] = w4.z;
        Ls[nl + 3][kl] = w4.w;
    }
    __syncthreads();
#pragma unroll
    for (int i = 0; i < 16; ++i) {
        int flat = i * 256 + t;
        int n = flat >> 6, kk = flat & 63;
        float val = Ls[n][kk];
        unsigned short hi = f2bf(val);
        if (z < 3) {
            WtH[(size_t)z * ND * ND + (size_t)(n0 + n) * ND + (k0 + kk)] = hi;
        } else {
            WtO[(size_t)(n0 + n) * K2 + (k0 + kk)]      = hi;
            WtO[(size_t)(n0 + n) * K2 + ND + (k0 + kk)] = f2bf(val - bf2f(hi));
        }
    }
}

// ---------------------------------------------------------------------------
// GEMM, m97 structure: 128x128 tile, BK=32, 4 waves, global_load_lds(16B).
// OUTMODE 0: C = x_hi @ WtH[z]^T + b  -> z 0/1: Q/K bf16 [B,H,S,DH];
//            z==2: V written TRANSPOSED as Vt [B,H,DH,S].  K = 1024.
// OUTMODE 1: C = A2 @ WtO^T + b (split hh+hl+lh, virtual K=3072) -> fp32 out.
// ---------------------------------------------------------------------------
template <int OUTMODE>
__global__ __launch_bounds__(256) void gemm_split(
    const ushortT* __restrict__ A2,   // OUTMODE0: [NM x ND] ; OUTMODE1: [NM x K2]
    const ushortT* __restrict__ Wt,   // OUTMODE0: WtH base ; OUTMODE1: WtO
    const float* __restrict__ b0, const float* __restrict__ b1, const float* __restrict__ b2,
    ushortT* __restrict__ Qo, ushortT* __restrict__ Ko, ushortT* __restrict__ Vtg,
    float* __restrict__ Ofp)
{
    const int z = blockIdx.z;
    const int AS = OUTMODE ? K2 : ND;   // row stride of A and B
    const ushortT* __restrict__ Bt = OUTMODE ? Wt : Wt + (size_t)z * ND * ND;
    const float* __restrict__ bias = (z == 0) ? b0 : (z == 1) ? b1 : b2;

    const int m0 = blockIdx.y * 128;
    const int n0 = blockIdx.x * 128;
    const int tid = threadIdx.x;
    const int lane = tid & 63, w = tid >> 6;
    const int wrow = w >> 1, wcol = w & 1;
    const int a = lane & 15, g = lane >> 4;

    __shared__ __align__(16) ushortT Abuf[128 * 32];
    __shared__ __align__(16) ushortT Bbuf[128 * 32];

    f32x4 acc[4][4] = {};

    const int srow_l = tid >> 2;
    const int scc0 = tid & 3;
    const int swz = (a >> 1) & 3;

    const int NSTEP = OUTMODE ? 96 : 32;
    for (int ks = 0; ks < NSTEP; ++ks) {
        const int kp = ks * 32;
        const int ac = OUTMODE ? ((kp < ND) ? kp : kp - ND) : kp;          // [hi,hi,lo]
        const int bc = OUTMODE ? ((kp < 2 * ND) ? kp : kp - 2 * ND) : kp;  // [hi,lo,hi]
        __syncthreads();
#pragma unroll
        for (int t = 0; t < 2; ++t) {
            int r = t * 64 + srow_l;
            int sc = scc0 ^ ((r >> 1) & 3);
            gl_lds16(&A2[(size_t)(m0 + r) * AS + ac + (sc << 3)],
                     &Abuf[(t * 256 + w * 64) * 8]);
            gl_lds16(&Bt[(size_t)(n0 + r) * AS + bc + (sc << 3)],
                     &Bbuf[(t * 256 + w * 64) * 8]);
        }
        __syncthreads();

        bf16x8 af[4], bfr[4];
#pragma unroll
        for (int i = 0; i < 4; ++i)
            af[i] = *(const bf16x8*)&Abuf[(wrow * 64 + i * 16 + a) * 32 + ((g ^ swz) << 3)];
#pragma unroll
        for (int j = 0; j < 4; ++j)
            bfr[j] = *(const bf16x8*)&Bbuf[(wcol * 64 + j * 16 + a) * 32 + ((g ^ swz) << 3)];
#pragma unroll
        for (int i = 0; i < 4; ++i)
#pragma unroll
            for (int j = 0; j < 4; ++j)
                acc[i][j] = __builtin_amdgcn_mfma_f32_16x16x32_bf16(af[i], bfr[j], acc[i][j], 0, 0, 0);
    }

    float bj[4];
#pragma unroll
    for (int j = 0; j < 4; ++j) bj[j] = bias[n0 + wcol * 64 + j * 16 + a];

#pragma unroll
    for (int i = 0; i < 4; ++i) {
#pragma unroll
        for (int r = 0; r < 4; ++r) {
            int grow = m0 + wrow * 64 + i * 16 + g * 4 + r;
#pragma unroll
            for (int j = 0; j < 4; ++j) {
                int gcol = n0 + wcol * 64 + j * 16 + a;
                float v = acc[i][j][r] + bj[j];
                if (OUTMODE == 1) {
                    Ofp[(size_t)grow * ND + gcol] = v;
                } else {
                    int b = grow >> 11, s = grow & (NS - 1);
                    int h = gcol >> 6, dh = gcol & 63;
                    if (z < 2) {
                        ushortT* dst = (z == 0) ? Qo : Ko;
                        dst[((size_t)(b * NH + h) * NS + s) * NDH + dh] = f2bf(v);
                    } else {
                        Vtg[((size_t)(b * NH + h) * NDH + dh) * NS + s] = f2bf(v);
                    }
                }
            }
        }
    }
}

// ---------------------------------------------------------------------------
// Flash attention, 32x32x16 MFMA, swapped QK^T (lane = q-row), in-register P.
// Block = 4 waves x 32 q-rows = 128 q. KV tile 64, double-buffered gl_lds.
// Output: gathered split [b, s, K2] (hi|lo planes) for the out-projection.
// ---------------------------------------------------------------------------
__global__ __launch_bounds__(256) void attn_fwd2(
    const ushortT* __restrict__ Q, const ushortT* __restrict__ K,
    const ushortT* __restrict__ Vt, ushortT* __restrict__ A2o)
{
    const int bh = blockIdx.y;
    const int b = bh >> 4, h = bh & 15;
    const int q0 = blockIdx.x * 128;
    const int tid = threadIdx.x, lane = tid & 63, w = tid >> 6;
    const int ql = lane & 31;   // this lane's q (col of St / O^T)
    const int hi = lane >> 5;

    // 32 KB total: [K dbuf 16KB | V dbuf 16KB]; reused as epilogue scratch
    __shared__ __align__(16) unsigned smem4[8192];
    ushortT* sK = (ushortT*)smem4;          // [2][64*64]
    ushortT* sV = sK + 2 * 4096;            // [2][64*64]

    const ushortT* __restrict__ Kb  = K  + (size_t)bh * NS * NDH;   // [s][64]
    const ushortT* __restrict__ Vtb = Vt + (size_t)bh * NDH * NS;   // [d][S]

    // Q fragments (B-operand): col=ql, k = hi*8+j -> d = kc*16 + hi*8 + j
    bf16x8 qf[4];
    {
        const ushortT* qrow = Q + (size_t)bh * NS * NDH + (size_t)(q0 + w * 32 + ql) * NDH + hi * 8;
#pragma unroll
        for (int kc = 0; kc < 4; ++kc) {
            qf[kc] = *(const bf16x8*)(qrow + kc * 16);
#pragma unroll
            for (int j = 0; j < 8; ++j)   // fold 1/sqrt(64) into Q (exact scale)
                qf[kc][j] = (short)f2bf(bf2f((ushortT)qf[kc][j]) * 0.125f);
        }
    }

    const int srw = lane >> 3;   // staging: row-in-group 0..7
    const int scc = lane & 7;    // staging: chunk 0..7

    float m_run = -INFINITY, l_run = 0.f;
    f32x16 oat[2] = {};

    // ---- stage tile 0 into buf 0 ----
#pragma unroll
    for (int c = 0; c < 2; ++c) {
        int rK = c * 32 + w * 8 + srw;
        gl_lds16(&Kb[(size_t)rK * NDH + ((scc ^ srw) << 3)], &sK[(c * 256 + w * 64) * 8]);
        gl_lds16(&Vtb[(size_t)rK * NS + ((scc ^ srw) << 3)], &sV[(c * 256 + w * 64) * 8]);
    }

    for (int t = 0; t < NS / 64; ++t) {
        const int cur = t & 1;
        __syncthreads();   // drains vmcnt -> buf[cur] ready; prev reads done
        if (t + 1 < NS / 64) {
            const int nxt = cur ^ 1;
            const int kv1 = (t + 1) * 64;
#pragma unroll
            for (int c = 0; c < 2; ++c) {
                int rK = c * 32 + w * 8 + srw;
                gl_lds16(&Kb[(size_t)(kv1 + rK) * NDH + ((scc ^ srw) << 3)],
                         &sK[(nxt * 4096) + (c * 256 + w * 64) * 8]);
                gl_lds16(&Vtb[(size_t)rK * NS + kv1 + ((scc ^ srw) << 3)],
                         &sV[(nxt * 4096) + (c * 256 + w * 64) * 8]);
            }
        }
        const ushortT* kbuf = sK + cur * 4096;
        const ushortT* vbuf = sV + cur * 4096;

        // ---- St[s] = K_sub @ Q^T : rows=kv, cols=q ----
        f32x16 st[2] = {};
#pragma unroll
        for (int s = 0; s < 2; ++s) {
            const int kv = s * 32 + ql;
#pragma unroll
            for (int kc = 0; kc < 4; ++kc) {
                bf16x8 kf = *(const bf16x8*)&kbuf[kv * 64 + (((kc * 2 + hi) ^ (ql & 7)) << 3)];
                st[s] = __builtin_amdgcn_mfma_f32_32x32x16_bf16(kf, qf[kc], st[s], 0, 0, 0);
            }
        }

        // ---- online softmax; lane owns q = ql (pair with lane^32) ----
        float mx = -INFINITY;
#pragma unroll
        for (int s = 0; s < 2; ++s)
#pragma unroll
            for (int r = 0; r < 16; ++r) mx = fmaxf(mx, st[s][r]);
        mx = fmaxf(mx, __shfl_xor(mx, 32));
        float mn = fmaxf(m_run, mx);
        float al = __expf(m_run - mn);
        float rs = 0.f;
#pragma unroll
        for (int s = 0; s < 2; ++s)
#pragma unroll
            for (int r = 0; r < 16; ++r) {
                float e = __expf(st[s][r] - mn);
                st[s][r] = e;
                rs += e;
            }
        rs += __shfl_xor(rs, 32);
        l_run = l_run * al + rs;
        m_run = mn;
#pragma unroll
        for (int dt = 0; dt < 2; ++dt)
#pragma unroll
            for (int r = 0; r < 16; ++r) oat[dt][r] *= al;

        // ---- O^T += V^T @ P^T : per 16-kv step, assemble P B-frag in-reg ----
#pragma unroll
        for (int ts = 0; ts < 4; ++ts) {
            const int s = ts >> 1, rb = 8 * (ts & 1);
            unsigned u0 = (unsigned)f2bf(st[s][rb + 0]) | ((unsigned)f2bf(st[s][rb + 1]) << 16);
            unsigned u1 = (unsigned)f2bf(st[s][rb + 2]) | ((unsigned)f2bf(st[s][rb + 3]) << 16);
            unsigned v0 = (unsigned)f2bf(st[s][rb + 4]) | ((unsigned)f2bf(st[s][rb + 5]) << 16);
            unsigned v1 = (unsigned)f2bf(st[s][rb + 6]) | ((unsigned)f2bf(st[s][rb + 7]) << 16);
            unsigned t0 = hi ? u0 : v0;
            unsigned t1 = hi ? u1 : v1;
            unsigned t0s = __shfl_xor(t0, 32);
            unsigned t1s = __shfl_xor(t1, 32);
            union { unsigned u[4]; bf16x8 v; } pf;
            pf.u[0] = hi ? t0s : u0;
            pf.u[1] = hi ? t1s : u1;
            pf.u[2] = hi ? v0 : t0s;
            pf.u[3] = hi ? v1 : t1s;
#pragma unroll
            for (int dt = 0; dt < 2; ++dt) {
                bf16x8 vf = *(const bf16x8*)&vbuf[(dt * 32 + ql) * 64 + (((ts * 2 + hi) ^ (ql & 7)) << 3)];
                oat[dt] = __builtin_amdgcn_mfma_f32_32x32x16_bf16(vf, pf.v, oat[dt], 0, 0, 0);
            }
        }
    }

    // ---- epilogue: O^T -> LDS (xor-swizzled) -> split hi/lo gathered store ----
    __syncthreads();
    unsigned* osc = smem4 + w * 2048;   // per-wave [32 q][64 d]
    float inv = 1.0f / l_run;
#pragma unroll
    for (int dt = 0; dt < 2; ++dt)
#pragma unroll
        for (int r = 0; r < 16; ++r) {
            int d = dt * 32 + (r & 3) + 8 * (r >> 2) + 4 * hi;
            float o = oat[dt][r] * inv;
            unsigned short hb = f2bf(o);
            unsigned short lb = f2bf(o - bf2f(hb));
            osc[ql * 64 + (d ^ ql)] = (unsigned)hb | ((unsigned)lb << 16);
        }
    __syncthreads();
    const int qrd = lane >> 3;
    const int dbase = (lane & 7) * 8;
#pragma unroll
    for (int p = 0; p < 4; ++p) {
        int q = p * 8 + qrd;
        unsigned wv[8];
#pragma unroll
        for (int k = 0; k < 8; ++k)
            wv[k] = osc[q * 64 + ((dbase + k) ^ q)];
        union { ushortT s[8]; bf16x8 v; } hs, ls;
#pragma unroll
        for (int k = 0; k < 8; ++k) {
            hs.s[k] = (ushortT)(wv[k] & 0xffffu);
            ls.s[k] = (ushortT)(wv[k] >> 16);
        }
        size_t row = (size_t)(b * NS + q0 + w * 32 + q) * K2 + h * 64 + dbase;
        *(bf16x8*)&A2o[row]      = hs.v;
        *(bf16x8*)&A2o[row + ND] = ls.v;
    }
}

// ---------------------------------------------------------------------------
extern "C" void kernel_launch(void* const* d_in, const int* in_sizes, int n_in,
                              void* d_out, int out_size, void* d_ws, size_t ws_size,
                              hipStream_t stream)
{
    const float* x  = (const float*)d_in[0];
    const float* Wq = (const float*)d_in[1];
    const float* bq = (const float*)d_in[2];
    const float* Wk = (const float*)d_in[3];
    const float* bk = (const float*)d_in[4];
    const float* Wv = (const float*)d_in[5];
    const float* bv = (const float*)d_in[6];
    const float* Wo = (const float*)d_in[7];
    const float* bo = (const float*)d_in[8];
    float* out = (float*)d_out;

    // ws: xh 8.4 | WtH 6.3 | WtO 4.2 | Q 8.4 | K 8.4 | Vt 8.4 | A2 16.8 = 60.8 MB
    ushortT* xh  = (ushortT*)d_ws;
    ushortT* WtH = xh  + (size_t)NM * ND;
    ushortT* WtO = WtH + (size_t)3 * ND * ND;
    ushortT* Qb  = WtO + (size_t)ND * K2;
    ushortT* Kb  = Qb  + (size_t)NM * ND;
    ushortT* Vtg = Kb  + (size_t)NM * ND;
    ushortT* A2  = Vtg + (size_t)NM * ND;

    split_x<<<dim3(NM * ND / 1024), 256, 0, stream>>>(x, xh);
    split_w_t<<<dim3(16, 16, 4), 256, 0, stream>>>(Wq, Wk, Wv, Wo, WtH, WtO);
    gemm_split<0><<<dim3(8, 32, 3), 256, 0, stream>>>(
        xh, WtH, bq, bk, bv, Qb, Kb, Vtg, nullptr);
    attn_fwd2<<<dim3(NS / 128, NB * NH), 256, 0, stream>>>(Qb, Kb, Vtg, A2);
    gemm_split<1><<<dim3(8, 32, 1), 256, 0, stream>>>(
        A2, WtO, bo, bo, bo, nullptr, nullptr, nullptr, out);
}